// Round 2
// baseline (419.891 us; speedup 1.0000x reference)
//
#include <hip/hip_runtime.h>
#include <math.h>

#define F_CH 12
#define C_DIM 200
#define HW 225
#define PERB (C_DIM*HW)      /* 45000 */
#define LN_EPS 1e-5f

/* ws layout (floats) */
#define WS_WT   0        /* 7200: wT[c][36] = {w11[:,c], w21[:,c], w31[:,c]} */
#define WS_DP   7200     /* 200:  D'[c] = d[c] - mean(d) */
#define WS_VARD 7400     /* 1:    mean(D'^2) */
#define WS_PB   7424     /* per-b: 896 floats each (PS 225, RS 225, Ag 200, Dg 200) */
#define PB_STRIDE 896

__global__ __launch_bounds__(256) void k_prep(
    const float* __restrict__ w11, const float* __restrict__ w21,
    const float* __restrict__ w31, const float* __restrict__ b41,
    const float* __restrict__ w42, const float* __restrict__ b42,
    float* __restrict__ wT, float* __restrict__ Dp, float* __restrict__ varD)
{
    const int tid = threadIdx.x;
    for (int i = tid; i < 36*C_DIM; i += 256) {
        int c = i / 36, g = i - 36*c;
        float v;
        if (g < 12)      v = w11[g*C_DIM + c];
        else if (g < 24) v = w21[(g-12)*C_DIM + c];
        else             v = w31[(g-24)*C_DIM + c];
        wT[i] = v;
    }
    __shared__ float red[12];
    __shared__ float DmSh;
    float d = 0.f;
    if (tid < C_DIM) {
        float s = b42[tid];
#pragma unroll
        for (int j = 0; j < 6; ++j) s = fmaf(w42[tid*6+j], b41[j], s);
        d = s;
    }
    float s0 = d;
    for (int o = 32; o > 0; o >>= 1) s0 += __shfl_down(s0, o, 64);
    if ((tid & 63) == 0) red[tid >> 6] = s0;
    __syncthreads();
    if (tid == 0) DmSh = (red[0]+red[1]+red[2]+red[3]) * (1.f/C_DIM);
    __syncthreads();
    float dp = (tid < C_DIM) ? (d - DmSh) : 0.f;
    if (tid < C_DIM) Dp[tid] = dp;
    float s1 = dp*dp;
    for (int o = 32; o > 0; o >>= 1) s1 += __shfl_down(s1, o, 64);
    if ((tid & 63) == 0) red[4 + (tid >> 6)] = s1;
    __syncthreads();
    if (tid == 0) varD[0] = (red[4]+red[5]+red[6]+red[7]) * (1.f/C_DIM);
}

/* Pass 1: per-b GEMM [225 x 200]x[200 x 36] + head math.
   Wave w owns output channels f in [9w, 9w+9); lane l owns pixels 4l..4l+3
   (lane >=56: scalar pixel 224). float4 X loads, 4 in flight. */
__global__ __launch_bounds__(256) void k_gemm(
    const float* __restrict__ X, const float* __restrict__ wT,
    const float* __restrict__ b11, const float* __restrict__ b21,
    const float* __restrict__ b31,
    const float* __restrict__ w41, const float* __restrict__ w42,
    const float* __restrict__ Dp, const float* __restrict__ varDp,
    const float* __restrict__ ln_g, const float* __restrict__ ln_b,
    float* __restrict__ ws)
{
    const int b    = blockIdx.x;
    const int tid  = threadIdx.x;
    const int lane = tid & 63;
    const int f0   = 9 * (int)__builtin_amdgcn_readfirstlane((unsigned)(threadIdx.x >> 6));

    __shared__ float accS[36][228];   /* padded row: 912 B, 16B-aligned rows */
    __shared__ float kqsS[HW];
    __shared__ float vmb[F_CH];
    __shared__ float vsS[F_CH];
    __shared__ float t1S[6];
    __shared__ float red[12];
    __shared__ float AmSh, varASh, covSh;

    const float* __restrict__ xb = X + (size_t)b * PERB;
    const bool vec = (lane < 56);
    const int  p0  = vec ? 4*lane : 224;

    float acc[9][4];
#pragma unroll
    for (int j = 0; j < 9; ++j)
#pragma unroll
        for (int e = 0; e < 4; ++e) acc[j][e] = 0.f;

    for (int cb = 0; cb < C_DIM; cb += 4) {
        float4 x0, x1, x2, x3;
        if (vec) {
            x0 = *(const float4*)(xb + (cb+0)*HW + p0);
            x1 = *(const float4*)(xb + (cb+1)*HW + p0);
            x2 = *(const float4*)(xb + (cb+2)*HW + p0);
            x3 = *(const float4*)(xb + (cb+3)*HW + p0);
        } else {
            float s0 = xb[(cb+0)*HW + 224];
            float s1 = xb[(cb+1)*HW + 224];
            float s2 = xb[(cb+2)*HW + 224];
            float s3 = xb[(cb+3)*HW + 224];
            x0 = make_float4(s0,s0,s0,s0);
            x1 = make_float4(s1,s1,s1,s1);
            x2 = make_float4(s2,s2,s2,s2);
            x3 = make_float4(s3,s3,s3,s3);
        }
        const float* wr0 = wT + (cb+0)*36 + f0;
        const float* wr1 = wT + (cb+1)*36 + f0;
        const float* wr2 = wT + (cb+2)*36 + f0;
        const float* wr3 = wT + (cb+3)*36 + f0;
#pragma unroll
        for (int j = 0; j < 9; ++j) {
            float w0 = wr0[j], w1 = wr1[j], w2 = wr2[j], w3 = wr3[j];
            acc[j][0] = fmaf(w0, x0.x, acc[j][0]);
            acc[j][1] = fmaf(w0, x0.y, acc[j][1]);
            acc[j][2] = fmaf(w0, x0.z, acc[j][2]);
            acc[j][3] = fmaf(w0, x0.w, acc[j][3]);
            acc[j][0] = fmaf(w1, x1.x, acc[j][0]);
            acc[j][1] = fmaf(w1, x1.y, acc[j][1]);
            acc[j][2] = fmaf(w1, x1.z, acc[j][2]);
            acc[j][3] = fmaf(w1, x1.w, acc[j][3]);
            acc[j][0] = fmaf(w2, x2.x, acc[j][0]);
            acc[j][1] = fmaf(w2, x2.y, acc[j][1]);
            acc[j][2] = fmaf(w2, x2.z, acc[j][2]);
            acc[j][3] = fmaf(w2, x2.w, acc[j][3]);
            acc[j][0] = fmaf(w3, x3.x, acc[j][0]);
            acc[j][1] = fmaf(w3, x3.y, acc[j][1]);
            acc[j][2] = fmaf(w3, x3.z, acc[j][2]);
            acc[j][3] = fmaf(w3, x3.w, acc[j][3]);
        }
    }

    /* store partials: lane<56 float4 rows, lane==56 scalar pixel 224 */
    if (vec) {
#pragma unroll
        for (int j = 0; j < 9; ++j) {
            float4 v = make_float4(acc[j][0], acc[j][1], acc[j][2], acc[j][3]);
            *(float4*)&accS[f0 + j][p0] = v;
        }
    } else if (lane == 56) {
#pragma unroll
        for (int j = 0; j < 9; ++j) accS[f0 + j][224] = acc[j][0];
    }
    if (tid < F_CH) vmb[tid] = 0.f;
    __syncthreads();

    /* kq per pixel + vm scramble buckets */
    if (tid < HW) {
        float kq = 0.f;
#pragma unroll
        for (int f = 0; f < F_CH; ++f) {
            float kf = accS[f][tid]      + b11[f];
            float qf = accS[12+f][tid]   + b21[f];
            kq = fmaf(kf, qf, kq);
        }
        kqsS[tid] = kq;

        float vf[F_CH];
#pragma unroll
        for (int f = 0; f < F_CH; ++f) vf[f] = accS[24+f][tid] + b31[f];
        int m0 = 12*tid;
        int a0 = m0/225, a1 = (m0+11)/225;
        if (a0 == a1) {
            float s = 0.f;
#pragma unroll
            for (int f = 0; f < F_CH; ++f) s += vf[f];
            atomicAdd(&vmb[a0], s);
        } else {
            int split = 225*a1 - m0;
            float sa = 0.f, sb = 0.f;
#pragma unroll
            for (int f = 0; f < F_CH; ++f) { if (f < split) sa += vf[f]; else sb += vf[f]; }
            atomicAdd(&vmb[a0], sa);
            atomicAdd(&vmb[a1], sb);
        }
    }
    __syncthreads();

    if (tid == 0) {
        float v[F_CH], mx = -1e30f;
#pragma unroll
        for (int a = 0; a < F_CH; ++a) { v[a] = vmb[a]*(1.f/HW); mx = fmaxf(mx, v[a]); }
        float s = 0.f;
#pragma unroll
        for (int a = 0; a < F_CH; ++a) { v[a] = __expf(v[a]-mx); s += v[a]; }
        float inv = __builtin_amdgcn_rcpf(s);
#pragma unroll
        for (int a = 0; a < F_CH; ++a) vsS[a] = v[a]*inv;
    }
    __syncthreads();

    if (tid < 6) {
        float s = 0.f;
#pragma unroll
        for (int l = 0; l < F_CH; ++l) s = fmaf(w41[tid*F_CH+l], vsS[l], s);
        t1S[tid] = s;
    }
    __syncthreads();

    float A = 0.f, AD = 0.f;
    if (tid < C_DIM) {
        float s = 0.f;
#pragma unroll
        for (int j = 0; j < 6; ++j) s = fmaf(w42[tid*6+j], t1S[j], s);
        A = s;
        AD = A * Dp[tid];
    }
    float r0 = A, r1 = A*A, r2 = AD;
    for (int o = 32; o > 0; o >>= 1) {
        r0 += __shfl_down(r0, o, 64);
        r1 += __shfl_down(r1, o, 64);
        r2 += __shfl_down(r2, o, 64);
    }
    if ((tid & 63) == 0) { int w = tid>>6; red[w*3]=r0; red[w*3+1]=r1; red[w*3+2]=r2; }
    __syncthreads();
    if (tid == 0) {
        float S0 = red[0]+red[3]+red[6]+red[9];
        float S1 = red[1]+red[4]+red[7]+red[10];
        float S2 = red[2]+red[5]+red[8]+red[11];
        float Am = S0*(1.f/C_DIM);
        AmSh   = Am;
        varASh = S1*(1.f/C_DIM) - Am*Am;
        covSh  = S2*(1.f/C_DIM);
    }
    __syncthreads();

    float* __restrict__ wsb = ws + WS_PB + (size_t)b * PB_STRIDE;
    if (tid < C_DIM) {
        float g = ln_g[tid];
        wsb[450 + tid] = (A - AmSh) * g;     /* Ag */
        wsb[650 + tid] = Dp[tid] * g;        /* Dg */
    }
    if (tid < HW) {
        float kq  = kqsS[tid];
        float var = fmaf(kq*kq, varASh, fmaf(2.f*kq, covSh, varDp[0]));
        float rs  = __builtin_amdgcn_rsqf(var + LN_EPS);
        wsb[tid]       = kq * rs;            /* PS */
        wsb[225 + tid] = rs;                 /* RS */
    }
}

/* Pass 2: gate-table streaming. 5 chunks of 40 c-rows (9000 floats).
   Phase A: gate[idx] with lane-consecutive LDS (conflict-free).
   Phase B: float4 X * float4 gate (ds_read_b128 lane-consecutive). */
__global__ __launch_bounds__(256) void k_apply(
    const float* __restrict__ X, const float* __restrict__ ws,
    const float* __restrict__ ln_b, float* __restrict__ out)
{
    const int b   = blockIdx.x;
    const int tid = threadIdx.x;

    __shared__ float gS[9000];
    __shared__ float PSs[HW], RSs[HW];
    __shared__ float AgS[C_DIM], DgS[C_DIM], blS[C_DIM];

    const float* __restrict__ wsb = ws + WS_PB + (size_t)b * PB_STRIDE;
    if (tid < HW)    { PSs[tid] = wsb[tid]; RSs[tid] = wsb[225+tid]; }
    if (tid < C_DIM) { AgS[tid] = wsb[450+tid]; DgS[tid] = wsb[650+tid]; blS[tid] = ln_b[tid]; }
    __syncthreads();

    const float* __restrict__ xb = X + (size_t)b * PERB;
    float* __restrict__ ob = out + (size_t)b * PERB;

    for (int chunk = 0; chunk < 5; ++chunk) {
        const int c0   = chunk * 40;
        const int base = chunk * 9000;
        for (unsigned i = tid; i < 9000u; i += 256u) {
            unsigned cl = i / 225u;
            unsigned nn = i - 225u*cl;
            unsigned c  = c0 + cl;
            float xn = fmaf(PSs[nn], AgS[c], fmaf(RSs[nn], DgS[c], blS[c]));
            float t  = fmaxf(xn, 0.f);
            float g  = __builtin_amdgcn_rcpf(1.f + __expf(-t));
            gS[i] = g;
        }
        __syncthreads();
        const float4* __restrict__ X4 = (const float4*)(xb + base);
        float4* __restrict__ O4 = (float4*)(ob + base);
        const float4* __restrict__ G4 = (const float4*)gS;
        for (unsigned i = tid; i < 2250u; i += 256u) {
            float4 xv = X4[i];
            float4 gv = G4[i];
            float4 ov;
            ov.x = xv.x * gv.x;
            ov.y = xv.y * gv.y;
            ov.z = xv.z * gv.z;
            ov.w = xv.w * gv.w;
            O4[i] = ov;
        }
        __syncthreads();
    }
}

extern "C" void kernel_launch(void* const* d_in, const int* in_sizes, int n_in,
                              void* d_out, int out_size, void* d_ws, size_t ws_size,
                              hipStream_t stream) {
    const float* X   = (const float*)d_in[0];
    const float* w11 = (const float*)d_in[1];
    const float* b11 = (const float*)d_in[2];
    const float* w21 = (const float*)d_in[3];
    const float* b21 = (const float*)d_in[4];
    const float* w31 = (const float*)d_in[5];
    const float* b31 = (const float*)d_in[6];
    const float* w41 = (const float*)d_in[7];
    const float* b41 = (const float*)d_in[8];
    const float* w42 = (const float*)d_in[9];
    const float* b42 = (const float*)d_in[10];
    const float* lng = (const float*)d_in[11];
    const float* lnb = (const float*)d_in[12];
    float* out = (float*)d_out;
    float* ws  = (float*)d_ws;

    hipLaunchKernelGGL(k_prep, dim3(1), dim3(256), 0, stream,
                       w11, w21, w31, b41, w42, b42,
                       ws + WS_WT, ws + WS_DP, ws + WS_VARD);
    hipLaunchKernelGGL(k_gemm, dim3(1024), dim3(256), 0, stream,
                       X, ws + WS_WT, b11, b21, b31, w41, w42,
                       ws + WS_DP, ws + WS_VARD, lng, lnb, ws);
    hipLaunchKernelGGL(k_apply, dim3(1024), dim3(256), 0, stream,
                       X, ws, lnb, out);
}